// Round 12
// baseline (3941.591 us; speedup 1.0000x reference)
//
#include <hip/hip_runtime.h>
#include <hip/hip_bf16.h>
#include <stdint.h>

// BlockDiagonalACDC: out = riffle(idct(gD(dct(gA(x))))) + bias
// out = x @ M + bias, M = blockdiag(A_g^T) C2^T blockdiag(D_g^T) C3^T P.
// Compose Mt = M^T on device (bf16, MFMA), then one 16384x4096x4096 GEMM.
// r12: big-GEMM kernel reshaped 256x128 / BK=32 / 48 KiB LDS -> 3 blocks/CU
// (TLP covers the entry drain; wave geometry and 62% LDS ratio-ceiling kept).

typedef __attribute__((ext_vector_type(8))) short bf16x8;
typedef __attribute__((ext_vector_type(4))) float f32x4;

static __device__ __forceinline__ unsigned short f2bf(float f) {
    union { float f; unsigned u; } v; v.f = f;
    unsigned r = v.u + 0x7FFFu + ((v.u >> 16) & 1u);   // RNE
    return (unsigned short)(r >> 16);
}

// ---- elementwise f32 -> bf16, 4 per thread ----
__global__ void k_cvt4(const float* __restrict__ in, unsigned short* __restrict__ out) {
    long long i = ((long long)blockIdx.x * 256 + threadIdx.x) * 4;
    float4 v = *(const float4*)(in + i);
    ushort4 o;
    o.x = f2bf(v.x); o.y = f2bf(v.y); o.z = f2bf(v.z); o.w = f2bf(v.w);
    *(ushort4*)(out + i) = o;
}

// ---- A[g][o][i] -> At_bf[g][i][o] ----
__global__ void k_cvt_At(const float* __restrict__ A, unsigned short* __restrict__ At) {
    int idx = blockIdx.x * 256 + threadIdx.x;
    int g = idx >> 14, o = (idx >> 7) & 127, i = idx & 127;
    At[(g << 14) + (i << 7) + o] = f2bf(A[idx]);
}

// ---- DCT-II matrix: C2[k][j] = 2*cos(pi*k*(2j+1)/8192), 4 j per thread ----
__global__ void k_gen_c2(unsigned short* __restrict__ C2) {
    int base = (blockIdx.x * 256 + threadIdx.x) * 4;
    int k = base >> 12, j0 = base & 4095;
    ushort4 o;
    #pragma unroll
    for (int t = 0; t < 4; ++t) {
        int m = (k * (2 * (j0 + t) + 1)) & 16383;
        float c = __cosf((float)m * 3.8349519697141029e-4f); // pi/8192
        ((unsigned short*)&o)[t] = f2bf(2.0f * c);
    }
    *(ushort4*)(C2 + base) = o;
}

// ---- inverse: C3[j][k] = (1/4096)*w_k*cos(pi*k*(2j+1)/8192), w_0=1/2 ----
__global__ void k_gen_c3(unsigned short* __restrict__ C3) {
    int base = (blockIdx.x * 256 + threadIdx.x) * 4;
    int j = base >> 12, k0 = base & 4095;
    ushort4 o;
    #pragma unroll
    for (int t = 0; t < 4; ++t) {
        int k = k0 + t;
        int m = (k * (2 * j + 1)) & 16383;
        float c = __cosf((float)m * 3.8349519697141029e-4f);
        float w = (k == 0) ? 0.5f : 1.0f;
        ((unsigned short*)&o)[t] = f2bf(c * w * (1.0f / 4096.0f));
    }
    *(ushort4*)(C3 + base) = o;
}

// ================= 128^2 kernel (stages A,B: small grouped GEMMs) ==========
template<int MODE>
__global__ __launch_bounds__(256) void k_gemm(
    const unsigned short* __restrict__ Aop, int lda, long long aGS,
    const unsigned short* __restrict__ Bop, int ldb, long long bGS,
    void* __restrict__ Cop, int ldc, long long cGS,
    int K, const float* __restrict__ bias)
{
    __shared__ unsigned short As[128 * 32];
    __shared__ unsigned short Bs[128 * 32];
    const int t = threadIdx.x;
    const int lane = t & 63;
    const int wave = t >> 6;
    const int wr = wave >> 1, wc = wave & 1;
    const int g = blockIdx.z;

    const unsigned short* Ap = Aop + (long long)g * aGS + (long long)blockIdx.y * 128 * lda;
    const unsigned short* Bp = Bop + (long long)g * bGS + (long long)blockIdx.x * 128 * ldb;

    const int srow = t >> 2;
    const int scol = (t & 3) * 8;
    unsigned short* ldsA = As + wave * 512;
    unsigned short* ldsB = Bs + wave * 512;

    f32x4 acc[4][4] = {};

    for (int k0 = 0; k0 < K; k0 += 32) {
        __syncthreads();
        #pragma unroll
        for (int h = 0; h < 2; ++h) {
            const unsigned short* ga = Ap + (long long)(h * 64 + srow) * lda + (k0 + scol);
            const unsigned short* gb = Bp + (long long)(h * 64 + srow) * ldb + (k0 + scol);
            __builtin_amdgcn_global_load_lds(
                (const __attribute__((address_space(1))) void*)ga,
                (__attribute__((address_space(3))) void*)(ldsA + h * 2048), 16, 0, 0);
            __builtin_amdgcn_global_load_lds(
                (const __attribute__((address_space(1))) void*)gb,
                (__attribute__((address_space(3))) void*)(ldsB + h * 2048), 16, 0, 0);
        }
        __syncthreads();

        const int fr = lane & 15, fq = lane >> 4;
        bf16x8 a[4], b[4];
        #pragma unroll
        for (int m = 0; m < 4; ++m)
            a[m] = *(const bf16x8*)(As + (wr * 64 + m * 16 + fr) * 32 + fq * 8);
        #pragma unroll
        for (int n = 0; n < 4; ++n)
            b[n] = *(const bf16x8*)(Bs + (wc * 64 + n * 16 + fr) * 32 + fq * 8);
        #pragma unroll
        for (int m = 0; m < 4; ++m)
            #pragma unroll
            for (int n = 0; n < 4; ++n)
                acc[m][n] = __builtin_amdgcn_mfma_f32_16x16x32_bf16(a[m], b[n], acc[m][n], 0, 0, 0);
    }

    const int fr = lane & 15, fq = lane >> 4;
    const int rowB = blockIdx.y * 128 + wr * 64;
    const int colB = blockIdx.x * 128 + wc * 64;

    if (MODE == 0) {
        unsigned short* C = (unsigned short*)Cop + (long long)g * cGS;
        #pragma unroll
        for (int m = 0; m < 4; ++m)
        #pragma unroll
        for (int n = 0; n < 4; ++n) {
            int crow = colB + n * 16 + fr;
            int ccol = rowB + m * 16 + fq * 4;
            ushort4 p;
            p.x = f2bf(acc[m][n][0]); p.y = f2bf(acc[m][n][1]);
            p.z = f2bf(acc[m][n][2]); p.w = f2bf(acc[m][n][3]);
            *(ushort4*)(C + (long long)crow * ldc + ccol) = p;
        }
    }
}

// ============ 256x128 kernel: BK=32, 48 KiB LDS, 3 blocks/CU ===============
// 4 waves (2M x 1N... 2x2 of 128x64? waves: wr=wave>>1 (2 M-halves),
// wc=wave&1 (2 N-halves)); per-wave tile 128x64 (same as r4/r11 geometry).
// LDS = 2 buf x (A 16K | B 8K) = 48 KiB -> 3 blocks/CU (TLP covers drains).
// Row = 64 B (4 chunks). Two-sided swizzle (slot-proof: 8 lanes per
// (row-parity, chunk) 4-bank slot = conflict-free):
//   LDS(row, c) = global(row, c ^ ((row>>1)&3));
//   fragment read chunk = fq ^ ((fr>>1)&3); DMA writes stay lane-linear.
// Per K-tile: stale vmcnt(0) -> ONE barrier -> stage t+1 (6 gll) ->
// 12 ds_read_b128 -> 32 MFMA (setprio-wrapped).
// MODE 0: bf16 store with riffle row-permutation; MODE 1: f32 + bias, NT.
template<int MODE>
__global__ __launch_bounds__(256, 3) void k_gemm256b(
    const unsigned short* __restrict__ Aop, int lda,
    const unsigned short* __restrict__ Bop, int ldb,
    void* __restrict__ Cop, int ldc,
    int K, int nby, const float* __restrict__ bias)
{
    __shared__ unsigned short smem[24576];   // 48 KiB
    const int tid  = threadIdx.x;
    const int lane = tid & 63;
    const int wave = tid >> 6;
    const int wr = wave >> 1, wc = wave & 1;
    const int fr = lane & 15, fq = lane >> 4;

    // T1 XCD swizzle (grid multiple of 8) + B-cluster (by fastest)
    const int nwg = gridDim.x;
    const int bid = blockIdx.x;
    const int swz = (bid & 7) * (nwg >> 3) + (bid >> 3);
    const int by = swz % nby, bx = swz / nby;

    const unsigned short* Ap = Aop + (long long)by * 256 * lda;
    const unsigned short* Bp = Bop + (long long)bx * 128 * ldb;

    // staging: thread tid handles chunk (row = j*64 + (tid>>2), c = tid&3);
    // source col chunk = c ^ ((row>>1)&3) = (tid&3)^((tid>>3)&3), j-invariant
    const int srow = tid >> 2;                              // 0..63
    const int scol = ((tid & 3) ^ ((tid >> 3) & 3)) << 3;   // elem offset
    const unsigned short* aSrc = Ap + (long long)srow * lda + scol;
    const unsigned short* bSrc = Bp + (long long)srow * ldb + scol;

    const char* sm = (const char*)smem;
    const int chnk = (fq ^ ((fr >> 1) & 3)) << 4;
    const int aOff = (wr * 128 + fr) * 64 + chnk;           // + m*1024
    const int bOff = 16384 + (wc * 64 + fr) * 64 + chnk;    // + n*1024

    f32x4 acc[8][4] = {};
    bf16x8 af[8], bb[4];

#define STG(K0, BUFB)                                                          \
    _Pragma("unroll")                                                          \
    for (int j = 0; j < 4; ++j)                                                \
        __builtin_amdgcn_global_load_lds(                                      \
            (const __attribute__((address_space(1))) void*)(aSrc + (long long)(j * 64) * lda + (K0)), \
            (__attribute__((address_space(3))) void*)((char*)smem + (BUFB) + j * 4096 + tid * 16), 16, 0, 0); \
    _Pragma("unroll")                                                          \
    for (int j = 0; j < 2; ++j)                                                \
        __builtin_amdgcn_global_load_lds(                                      \
            (const __attribute__((address_space(1))) void*)(bSrc + (long long)(j * 64) * ldb + (K0)), \
            (__attribute__((address_space(3))) void*)((char*)smem + (BUFB) + 16384 + j * 4096 + tid * 16), 16, 0, 0);

#define BAR asm volatile("s_barrier" ::: "memory")

    STG(0, 0)                      // prologue: tile 0 -> buf 0

    const int nt = K >> 5;
    for (int t = 0; t < nt; ++t) {
        const int bo = (t & 1) * 24576;

        // entry: drain own tile-t loads (issued one tile ago; t=0 pays full
        // latency once). TLP from 3 blocks/CU covers the wait.
        asm volatile("s_waitcnt vmcnt(0)" ::: "memory");
        BAR;   // buf[t&1] collectively valid; all waves past t-1 reads

        if (t + 1 < nt) { STG((t + 1) << 5, ((t + 1) & 1) * 24576) }

        #pragma unroll
        for (int n = 0; n < 4; ++n)
            bb[n] = *(const bf16x8*)(sm + bo + bOff + n * 1024);
        #pragma unroll
        for (int m = 0; m < 8; ++m)
            af[m] = *(const bf16x8*)(sm + bo + aOff + m * 1024);

        __builtin_amdgcn_s_setprio(1);
        #pragma unroll
        for (int m = 0; m < 8; ++m)
            #pragma unroll
            for (int n = 0; n < 4; ++n)
                acc[m][n] = __builtin_amdgcn_mfma_f32_16x16x32_bf16(af[m], bb[n], acc[m][n], 0, 0, 0);
        __builtin_amdgcn_s_setprio(0);
    }
#undef STG
#undef BAR

    const int rB = by * 256 + wr * 128 + fq * 4;
    const int cB = bx * 128 + wc * 64 + fr;
    if (MODE == 0) {
        unsigned short* C = (unsigned short*)Cop;
        #pragma unroll
        for (int m = 0; m < 8; ++m)
        #pragma unroll
        for (int n = 0; n < 4; ++n)
        #pragma unroll
        for (int q = 0; q < 4; ++q) {
            int r = rB + m * 16 + q;
            int rr = (r & 1) ? (2048 + (r >> 1)) : (r >> 1);   // riffle fold
            C[(long long)rr * ldc + cB + n * 16] = f2bf(acc[m][n][q]);
        }
    } else {
        float* C = (float*)Cop;
        #pragma unroll
        for (int n = 0; n < 4; ++n) {
            float bv = bias[cB + n * 16];
            #pragma unroll
            for (int m = 0; m < 8; ++m)
            #pragma unroll
            for (int q = 0; q < 4; ++q)
                __builtin_nontemporal_store(acc[m][n][q] + bv,
                    &C[(long long)(rB + m * 16 + q) * ldc + cB + n * 16]);
        }
    }
}

extern "C" void kernel_launch(void* const* d_in, const int* in_sizes, int n_in,
                              void* d_out, int out_size, void* d_ws, size_t ws_size,
                              hipStream_t stream) {
    const float* x    = (const float*)d_in[0];
    const float* Af   = (const float*)d_in[1];
    const float* Dfm  = (const float*)d_in[2];
    const float* bias = (const float*)d_in[3];
    float* out = (float*)d_out;
    char* ws = (char*)d_ws;

    unsigned short* Xbf = (unsigned short*)(ws);                              // 128 MiB
    unsigned short* B1  = (unsigned short*)(ws + 134217728ULL);               // 32 MiB: C2, then Vt2
    unsigned short* B2  = (unsigned short*)(ws + 134217728ULL + 33554432ULL); // 32 MiB: C3
    unsigned short* B3  = (unsigned short*)(ws + 134217728ULL + 67108864ULL); // 32 MiB: Vt1, then Mt
    unsigned short* Atb = (unsigned short*)(ws + 134217728ULL + 100663296ULL);// 1 MiB
    unsigned short* Dtb = Atb + 524288;                                       // 1 MiB

    k_cvt4  <<<65536, 256, 0, stream>>>(x, Xbf);
    k_cvt4  <<<512,   256, 0, stream>>>(Dfm, Dtb);
    k_cvt_At<<<2048,  256, 0, stream>>>(Af, Atb);
    k_gen_c2<<<16384, 256, 0, stream>>>(B1);
    k_gen_c3<<<16384, 256, 0, stream>>>(B2);

    // Stage A (per group): V1_g[k,i] = sum_o C2[k, g*128+o] * A[g,o,i]; V1^T -> B3
    k_gemm<0><<<dim3(1, 32, 32), 256, 0, stream>>>(
        B1, 4096, 128LL,  Atb, 128, 16384LL,  B3, 4096, 524288LL, 128, nullptr);

    // Stage B (per group): V2[g*128+o, c] = sum_i D[g,o,i] * V1[g*128+i, c]; V2^T -> B1
    k_gemm<0><<<dim3(32, 1, 32), 256, 0, stream>>>(
        Dtb, 128, 16384LL,  B3, 4096, 128LL,  B1, 4096, 128LL, 128, nullptr);

    // Stage C (4096^3): Mt = riffle(C3 @ V2) -> B3. Grid 16by x 32bx = 512.
    k_gemm256b<0><<<512, 256, 0, stream>>>(B2, 4096, B1, 4096, B3, 4096, 4096, 16, nullptr);

    // Final (16384x4096x4096): OUT = X @ Mt^T + bias. Grid 64by x 32bx = 2048.
    k_gemm256b<1><<<2048, 256, 0, stream>>>(Xbf, 4096, B3, 4096, out, 4096, 4096, 64, bias);
}

// Round 14
// 698.505 us; speedup vs baseline: 5.6429x; 5.6429x over previous
//
#include <hip/hip_runtime.h>
#include <hip/hip_bf16.h>
#include <stdint.h>

// BlockDiagonalACDC: out = riffle(idct(gD(dct(gA(x))))) + bias
// Everything is linear per row => out = x @ M + bias with
// M = blockdiag(A_g^T) @ C2^T @ blockdiag(D_g^T) @ C3^T @ P  (4096x4096).
// Compose Mt = M^T on device (bf16, MFMA), then one 16384x4096x4096 GEMM.
// r14 = r11 core (best verified: 713 us) + vectorized gen kernels.
// (r13's crash was a grid-size transcription error: 2048 instead of 1024 on
// the final GEMM -> bx up to 31 > nbx-1=15 -> OOB writes past d_out.)

typedef __attribute__((ext_vector_type(8))) short bf16x8;
typedef __attribute__((ext_vector_type(4))) float f32x4;

static __device__ __forceinline__ unsigned short f2bf(float f) {
    union { float f; unsigned u; } v; v.f = f;
    unsigned r = v.u + 0x7FFFu + ((v.u >> 16) & 1u);   // RNE
    return (unsigned short)(r >> 16);
}

// ---- elementwise f32 -> bf16, 4 per thread ----
__global__ void k_cvt4(const float* __restrict__ in, unsigned short* __restrict__ out) {
    long long i = ((long long)blockIdx.x * 256 + threadIdx.x) * 4;
    float4 v = *(const float4*)(in + i);
    ushort4 o;
    o.x = f2bf(v.x); o.y = f2bf(v.y); o.z = f2bf(v.z); o.w = f2bf(v.w);
    *(ushort4*)(out + i) = o;
}

// ---- A[g][o][i] -> At_bf[g][i][o] ----
__global__ void k_cvt_At(const float* __restrict__ A, unsigned short* __restrict__ At) {
    int idx = blockIdx.x * 256 + threadIdx.x;
    int g = idx >> 14, o = (idx >> 7) & 127, i = idx & 127;
    At[(g << 14) + (i << 7) + o] = f2bf(A[idx]);
}

// ---- DCT-II matrix: C2[k][j] = 2*cos(pi*k*(2j+1)/8192), 4 j per thread ----
__global__ void k_gen_c2(unsigned short* __restrict__ C2) {
    int base = (blockIdx.x * 256 + threadIdx.x) * 4;
    int k = base >> 12, j0 = base & 4095;
    ushort4 o;
    #pragma unroll
    for (int t = 0; t < 4; ++t) {
        int m = (k * (2 * (j0 + t) + 1)) & 16383;
        float c = __cosf((float)m * 3.8349519697141029e-4f); // pi/8192
        ((unsigned short*)&o)[t] = f2bf(2.0f * c);
    }
    *(ushort4*)(C2 + base) = o;
}

// ---- inverse: C3[j][k] = (1/4096)*w_k*cos(pi*k*(2j+1)/8192), w_0=1/2 ----
__global__ void k_gen_c3(unsigned short* __restrict__ C3) {
    int base = (blockIdx.x * 256 + threadIdx.x) * 4;
    int j = base >> 12, k0 = base & 4095;
    ushort4 o;
    #pragma unroll
    for (int t = 0; t < 4; ++t) {
        int k = k0 + t;
        int m = (k * (2 * j + 1)) & 16383;
        float c = __cosf((float)m * 3.8349519697141029e-4f);
        float w = (k == 0) ? 0.5f : 1.0f;
        ((unsigned short*)&o)[t] = f2bf(c * w * (1.0f / 4096.0f));
    }
    *(ushort4*)(C3 + base) = o;
}

// ================= 128^2 kernel (stages A,B: small grouped GEMMs) ==========
template<int MODE>
__global__ __launch_bounds__(256) void k_gemm(
    const unsigned short* __restrict__ Aop, int lda, long long aGS,
    const unsigned short* __restrict__ Bop, int ldb, long long bGS,
    void* __restrict__ Cop, int ldc, long long cGS,
    int K, const float* __restrict__ bias)
{
    __shared__ unsigned short As[128 * 32];
    __shared__ unsigned short Bs[128 * 32];
    const int t = threadIdx.x;
    const int lane = t & 63;
    const int wave = t >> 6;
    const int wr = wave >> 1, wc = wave & 1;
    const int g = blockIdx.z;

    const unsigned short* Ap = Aop + (long long)g * aGS + (long long)blockIdx.y * 128 * lda;
    const unsigned short* Bp = Bop + (long long)g * bGS + (long long)blockIdx.x * 128 * ldb;

    const int srow = t >> 2;
    const int scol = (t & 3) * 8;
    unsigned short* ldsA = As + wave * 512;
    unsigned short* ldsB = Bs + wave * 512;

    f32x4 acc[4][4] = {};

    for (int k0 = 0; k0 < K; k0 += 32) {
        __syncthreads();
        #pragma unroll
        for (int h = 0; h < 2; ++h) {
            const unsigned short* ga = Ap + (long long)(h * 64 + srow) * lda + (k0 + scol);
            const unsigned short* gb = Bp + (long long)(h * 64 + srow) * ldb + (k0 + scol);
            __builtin_amdgcn_global_load_lds(
                (const __attribute__((address_space(1))) void*)ga,
                (__attribute__((address_space(3))) void*)(ldsA + h * 2048), 16, 0, 0);
            __builtin_amdgcn_global_load_lds(
                (const __attribute__((address_space(1))) void*)gb,
                (__attribute__((address_space(3))) void*)(ldsB + h * 2048), 16, 0, 0);
        }
        __syncthreads();

        const int fr = lane & 15, fq = lane >> 4;
        bf16x8 a[4], b[4];
        #pragma unroll
        for (int m = 0; m < 4; ++m)
            a[m] = *(const bf16x8*)(As + (wr * 64 + m * 16 + fr) * 32 + fq * 8);
        #pragma unroll
        for (int n = 0; n < 4; ++n)
            b[n] = *(const bf16x8*)(Bs + (wc * 64 + n * 16 + fr) * 32 + fq * 8);
        #pragma unroll
        for (int m = 0; m < 4; ++m)
            #pragma unroll
            for (int n = 0; n < 4; ++n)
                acc[m][n] = __builtin_amdgcn_mfma_f32_16x16x32_bf16(a[m], b[n], acc[m][n], 0, 0, 0);
    }

    const int fr = lane & 15, fq = lane >> 4;
    const int rowB = blockIdx.y * 128 + wr * 64;
    const int colB = blockIdx.x * 128 + wc * 64;

    if (MODE == 0) {
        unsigned short* C = (unsigned short*)Cop + (long long)g * cGS;
        #pragma unroll
        for (int m = 0; m < 4; ++m)
        #pragma unroll
        for (int n = 0; n < 4; ++n) {
            int crow = colB + n * 16 + fr;
            int ccol = rowB + m * 16 + fq * 4;
            ushort4 p;
            p.x = f2bf(acc[m][n][0]); p.y = f2bf(acc[m][n][1]);
            p.z = f2bf(acc[m][n][2]); p.w = f2bf(acc[m][n][3]);
            *(ushort4*)(C + (long long)crow * ldc + ccol) = p;
        }
    }
}

// ================= 256^2 kernel: r4 frame (verified), B-clustered order ====
// Tile 256x256, BK=64, 8 waves (2M x 4N), per-wave 128x64, LDS 128 KiB dbuf.
// Per K-tile: stale vmcnt(0) (own loads issued one full tile ago) -> ONE
// barrier -> stage next tile (8 global_load_lds) -> 24 ds_read_b128 up front
// -> 4 MFMA quadrants (compiler inserts counted lgkmcnt per quadrant).
// Block order: consecutive swz within an XCD share bx (B-panel, 2 MB -> L2
// resident, reused 32x/round); A-panels shared ACROSS XCDs via L3.
// MODE 0: bf16 store with riffle row-permutation; MODE 1: f32 + bias, NT.
template<int MODE>
__global__ __launch_bounds__(512, 2) void k_gemm256(
    const unsigned short* __restrict__ Aop, int lda,
    const unsigned short* __restrict__ Bop, int ldb,
    void* __restrict__ Cop, int ldc,
    int K, int nby, const float* __restrict__ bias)
{
    __shared__ unsigned short smem[65536];   // 128 KiB: [buf2][A 32KB | B 32KB]
    const int tid  = threadIdx.x;
    const int lane = tid & 63;
    const int wave = tid >> 6;
    const int wr = wave >> 2, wc = wave & 3;
    const int fr = lane & 15, fq = lane >> 4;

    // T1: bijective XCD swizzle (grid multiple of 8), then B-cluster:
    // by fastest -> consecutive swz share bx.
    const int nwg = gridDim.x;
    const int bid = blockIdx.x;
    const int swz = (bid & 7) * (nwg >> 3) + (bid >> 3);
    const int by = swz % nby, bx = swz / nby;

    const unsigned short* Ap = Aop + (long long)by * 256 * lda;
    const unsigned short* Bp = Bop + (long long)bx * 256 * ldb;

    // staging: lane tid writes LDS chunk tid; source col inverse-swizzled (T2)
    const int srow = tid >> 3;                       // 0..63
    const int scol = ((tid & 7) ^ (srow & 7)) << 3;  // element col (8-chunk)
    const unsigned short* aSrc = Ap + (long long)srow * lda + scol;
    const unsigned short* bSrc = Bp + (long long)srow * ldb + scol;

    const char* sm = (const char*)smem;
    const int aB0 = wr * 16384 + fr * 128;                             // bytes
    const int bB0 = 32768 + (wc >> 1) * 16384 + (wc & 1) * 8192 + fr * 128;
    const int swz0 = ((fq) ^ (fr & 7)) << 4;        // kk=0 swizzled chunk
    const int swz1 = ((4 + fq) ^ (fr & 7)) << 4;    // kk=1

    f32x4 acc[8][4] = {};
    bf16x8 af[2][4][2];   // [MH][i][kk]  A panel: 16 b128
    bf16x8 bb[2][2][2];   // [NH][jj][kk] B panel:  8 b128

#define STAGE(SRC, LD, H, K0, LDSS)                                            \
    _Pragma("unroll")                                                          \
    for (int j = 0; j < 2; ++j)                                                \
        __builtin_amdgcn_global_load_lds(                                      \
            (const __attribute__((address_space(1))) void*)(SRC + (long long)((H) * 128 + j * 64) * (LD) + (K0)), \
            (__attribute__((address_space(3))) void*)(smem + (LDSS) + j * 4096 + wave * 512), \
            16, 0, 0);

#define READ_A(MH, BO)                                                         \
    _Pragma("unroll")                                                          \
    for (int i = 0; i < 4; ++i) {                                              \
        af[MH][i][0] = *(const bf16x8*)(sm + (BO) + aB0 + ((MH) * 4 + i) * 2048 + swz0); \
        af[MH][i][1] = *(const bf16x8*)(sm + (BO) + aB0 + ((MH) * 4 + i) * 2048 + swz1); \
    }

#define READ_B(NH, BO)                                                         \
    _Pragma("unroll")                                                          \
    for (int jj = 0; jj < 2; ++jj) {                                           \
        bb[NH][jj][0] = *(const bf16x8*)(sm + (BO) + bB0 + ((NH) * 2 + jj) * 2048 + swz0); \
        bb[NH][jj][1] = *(const bf16x8*)(sm + (BO) + bB0 + ((NH) * 2 + jj) * 2048 + swz1); \
    }

#define MFMA_Q(MH, NH)                                                         \
    __builtin_amdgcn_s_setprio(1);                                             \
    _Pragma("unroll")                                                          \
    for (int i = 0; i < 4; ++i)                                                \
        _Pragma("unroll")                                                      \
        for (int jj = 0; jj < 2; ++jj) {                                       \
            acc[(MH) * 4 + i][(NH) * 2 + jj] = __builtin_amdgcn_mfma_f32_16x16x32_bf16(af[MH][i][0], bb[NH][jj][0], acc[(MH) * 4 + i][(NH) * 2 + jj], 0, 0, 0); \
            acc[(MH) * 4 + i][(NH) * 2 + jj] = __builtin_amdgcn_mfma_f32_16x16x32_bf16(af[MH][i][1], bb[NH][jj][1], acc[(MH) * 4 + i][(NH) * 2 + jj], 0, 0, 0); \
        }                                                                      \
    __builtin_amdgcn_s_setprio(0);

#define BAR asm volatile("s_barrier" ::: "memory")

    // prologue: stage K-tile 0 into buffer 0 (order A0,A1,B0,B1)
    STAGE(aSrc, lda, 0, 0, 0)
    STAGE(aSrc, lda, 1, 0, 8192)
    STAGE(bSrc, ldb, 0, 0, 16384)
    STAGE(bSrc, ldb, 1, 0, 24576)

    const int nt = K >> 6;
    for (int t = 0; t < nt; ++t) {
        const int bo = (t & 1) << 16;        // read-buffer byte offset
        const int ns = ((t + 1) & 1) << 15;  // stage-buffer short offset
        const int k1 = (t + 1) << 6;
        const bool hn = (t + 1) < nt;

        // entry: drain OWN tile-t loads (issued one full tile ago -> stale)
        asm volatile("s_waitcnt vmcnt(0)" ::: "memory");
        BAR;   // buf[t&1] collectively valid; all waves past tile t-1 reads

        // next-tile stages: in flight under this entire K-tile
        if (hn) {
            STAGE(aSrc, lda, 0, k1, ns)
            STAGE(aSrc, lda, 1, k1, ns + 8192)
            STAGE(bSrc, ldb, 0, k1, ns + 16384)
            STAGE(bSrc, ldb, 1, k1, ns + 24576)
        }

        // entire K-tile's fragment reads up front (24 x ds_read_b128);
        // order matches quadrant consumption: compiler emits counted lgkmcnt.
        READ_A(0, bo)
        READ_B(0, bo)
        READ_B(1, bo)
        READ_A(1, bo)

        MFMA_Q(0, 0)
        MFMA_Q(0, 1)
        MFMA_Q(1, 1)
        MFMA_Q(1, 0)
    }
#undef STAGE
#undef READ_A
#undef READ_B
#undef MFMA_Q
#undef BAR

    const int rB = by * 256 + wr * 128 + fq * 4;
    const int cB = bx * 256 + wc * 64 + fr;
    if (MODE == 0) {
        unsigned short* C = (unsigned short*)Cop;
        #pragma unroll
        for (int m = 0; m < 8; ++m)
        #pragma unroll
        for (int n = 0; n < 4; ++n)
        #pragma unroll
        for (int q = 0; q < 4; ++q) {
            int r = rB + m * 16 + q;
            int rr = (r & 1) ? (2048 + (r >> 1)) : (r >> 1);   // riffle fold
            C[(long long)rr * ldc + cB + n * 16] = f2bf(acc[m][n][q]);
        }
    } else {
        float* C = (float*)Cop;
        #pragma unroll
        for (int n = 0; n < 4; ++n) {
            float bv = bias[cB + n * 16];
            #pragma unroll
            for (int m = 0; m < 8; ++m)
            #pragma unroll
            for (int q = 0; q < 4; ++q)
                __builtin_nontemporal_store(acc[m][n][q] + bv,
                    &C[(long long)(rB + m * 16 + q) * ldc + cB + n * 16]);
        }
    }
}

extern "C" void kernel_launch(void* const* d_in, const int* in_sizes, int n_in,
                              void* d_out, int out_size, void* d_ws, size_t ws_size,
                              hipStream_t stream) {
    const float* x    = (const float*)d_in[0];
    const float* Af   = (const float*)d_in[1];
    const float* Dfm  = (const float*)d_in[2];
    const float* bias = (const float*)d_in[3];
    float* out = (float*)d_out;
    char* ws = (char*)d_ws;

    unsigned short* Xbf = (unsigned short*)(ws);                              // 128 MiB
    unsigned short* B1  = (unsigned short*)(ws + 134217728ULL);               // 32 MiB: C2, then Vt2
    unsigned short* B2  = (unsigned short*)(ws + 134217728ULL + 33554432ULL); // 32 MiB: C3
    unsigned short* B3  = (unsigned short*)(ws + 134217728ULL + 67108864ULL); // 32 MiB: Vt1, then Mt
    unsigned short* Atb = (unsigned short*)(ws + 134217728ULL + 100663296ULL);// 1 MiB
    unsigned short* Dtb = Atb + 524288;                                       // 1 MiB

    k_cvt4  <<<65536, 256, 0, stream>>>(x, Xbf);
    k_cvt4  <<<512,   256, 0, stream>>>(Dfm, Dtb);
    k_cvt_At<<<2048,  256, 0, stream>>>(Af, Atb);
    k_gen_c2<<<16384, 256, 0, stream>>>(B1);
    k_gen_c3<<<16384, 256, 0, stream>>>(B2);

    // Stage A (per group): V1_g[k,i] = sum_o C2[k, g*128+o] * A[g,o,i]; V1^T -> B3
    k_gemm<0><<<dim3(1, 32, 32), 256, 0, stream>>>(
        B1, 4096, 128LL,  Atb, 128, 16384LL,  B3, 4096, 524288LL, 128, nullptr);

    // Stage B (per group): V2[g*128+o, c] = sum_i D[g,o,i] * V1[g*128+i, c]; V2^T -> B1
    k_gemm<0><<<dim3(32, 1, 32), 256, 0, stream>>>(
        Dtb, 128, 16384LL,  B3, 4096, 128LL,  B1, 4096, 128LL, 128, nullptr);

    // Stage C (4096^3): V3[j,c] = sum_k C3[j,k] * V2[k,c]; riffle rows -> Mt (B3)
    // grid = 16 nby x 16 nbx = 256
    k_gemm256<0><<<256, 512, 0, stream>>>(B2, 4096, B1, 4096, B3, 4096, 4096, 16, nullptr);

    // Final (16384x4096x4096): OUT[r,n] = sum_k Xbf[r,k] * Mt[n,k] + bias[n]
    // grid = 64 nby x 16 nbx = 1024; consecutive swz share bx -> Mt L2-resident
    k_gemm256<1><<<1024, 512, 0, stream>>>(Xbf, 4096, B3, 4096, out, 4096, 4096, 64, bias);
}